// Round 1
// baseline (242.688 us; speedup 1.0000x reference)
//
#include <hip/hip_runtime.h>
#include <math.h>

// Problem constants (match reference setup_inputs)
#define B_  128
#define S_  512
#define D_  768
#define M_  64   // MAX_CLS

// Kernel A: one wave (64 threads) per batch row.
// Computes ascending positions of set cls bits (first M_ of them) and the count.
__global__ void Summarizer_pos_kernel(const int* __restrict__ cls,
                                      int* __restrict__ pos,
                                      int* __restrict__ cnt) {
    const int b    = blockIdx.x;
    const int lane = threadIdx.x;          // 0..63
    const int* row = cls + (size_t)b * S_;

    int base = 0;
    #pragma unroll
    for (int i = 0; i < S_ / 64; ++i) {
        const int v = row[i * 64 + lane];
        const unsigned long long mask = __ballot(v != 0);
        const unsigned long long below = (lane == 0) ? 0ull
                                        : (mask & ((1ull << lane) - 1ull));
        const int rank = base + __popcll(below);
        if (v != 0 && rank < M_) {
            pos[(size_t)b * M_ + rank] = i * 64 + lane;
        }
        base += __popcll(mask);
    }
    if (lane == 0) cnt[b] = (base < M_) ? base : M_;
}

// Kernel B: one wave per (batch, m) pair. 768-elem dot + sigmoid.
// Row viewed as 192 float4; lane l loads float4 indices l, l+64, l+128 (fully coalesced).
__global__ void Summarizer_dot_kernel(const float* __restrict__ enc,
                                      const float* __restrict__ W,
                                      const float* __restrict__ bias,
                                      const int* __restrict__ pos,
                                      const int* __restrict__ cnt,
                                      float* __restrict__ out) {
    const int tid  = blockIdx.x * blockDim.x + threadIdx.x;
    const int wid  = tid >> 6;             // global wave id = b*M_ + m
    const int lane = tid & 63;
    const int b    = wid >> 6;             // wid / M_
    const int m    = wid & (M_ - 1);       // wid % M_

    float sum = 0.0f;
    const int count = cnt[b];
    if (m < count) {
        const int p = pos[(size_t)b * M_ + m];
        const float4* row4 = (const float4*)(enc + ((size_t)b * S_ + p) * D_);
        const float4* w4   = (const float4*)W;

        const float4 r0 = row4[lane];
        const float4 r1 = row4[lane + 64];
        const float4 r2 = row4[lane + 128];
        const float4 w0 = w4[lane];
        const float4 w1 = w4[lane + 64];
        const float4 w2 = w4[lane + 128];

        sum = r0.x * w0.x + r0.y * w0.y + r0.z * w0.z + r0.w * w0.w
            + r1.x * w1.x + r1.y * w1.y + r1.z * w1.z + r1.w * w1.w
            + r2.x * w2.x + r2.y * w2.y + r2.z * w2.z + r2.w * w2.w;
    }

    // 64-lane reduction
    #pragma unroll
    for (int off = 32; off > 0; off >>= 1) {
        sum += __shfl_down(sum, off, 64);
    }

    if (lane == 0) {
        const float x = sum + bias[0];
        out[wid] = 1.0f / (1.0f + __expf(-x));
    }
}

extern "C" void kernel_launch(void* const* d_in, const int* in_sizes, int n_in,
                              void* d_out, int out_size, void* d_ws, size_t ws_size,
                              hipStream_t stream) {
    const float* enc  = (const float*)d_in[0];   // (B,S,D) fp32
    const float* W    = (const float*)d_in[1];   // (D,1)  fp32
    const float* bias = (const float*)d_in[2];   // (1,)   fp32
    const int*   cls  = (const int*)d_in[3];     // (B,S)  bool -> int32 per harness
    float* out = (float*)d_out;                  // (B,M,1) fp32

    int* pos = (int*)d_ws;                       // B*M ints = 32 KB
    int* cnt = pos + (size_t)B_ * M_;            // B ints

    Summarizer_pos_kernel<<<B_, 64, 0, stream>>>(cls, pos, cnt);

    const int total_threads = B_ * M_ * 64;      // one wave per (b,m)
    Summarizer_dot_kernel<<<total_threads / 256, 256, 0, stream>>>(
        enc, W, bias, pos, cnt, out);
}

// Round 2
// 240.778 us; speedup vs baseline: 1.0079x; 1.0079x over previous
//
#include <hip/hip_runtime.h>
#include <math.h>

// Problem constants (match reference setup_inputs)
#define B_  128
#define S_  512
#define D_  768
#define M_  64   // MAX_CLS

// Fused kernel: 2 blocks per batch (blockIdx.x = b*2 + half), 256 threads.
// Phase 1: wave 0 computes ascending positions of set cls bits into LDS.
// Phase 2: each of the 4 waves handles m-slots (half*32 + it*4 + wave),
//          768-elem dot against W (held in registers) + sigmoid.
__global__ __launch_bounds__(256) void Summarizer_fused_kernel(
    const float* __restrict__ enc,
    const float* __restrict__ W,
    const float* __restrict__ bias,
    const int*   __restrict__ cls,
    float*       __restrict__ out) {

    __shared__ int s_pos[M_];
    __shared__ int s_cnt;

    const int tid  = threadIdx.x;
    const int lane = tid & 63;
    const int wave = tid >> 6;              // 0..3
    const int b    = blockIdx.x >> 1;
    const int half = blockIdx.x & 1;        // which 32 m-slots this block owns

    // ---- Phase 1: wave 0 builds the position list (stable ascending) ----
    if (wave == 0) {
        const int* row = cls + (size_t)b * S_;
        int base = 0;
        #pragma unroll
        for (int i = 0; i < S_ / 64; ++i) {
            const int v = row[i * 64 + lane];
            const unsigned long long mask  = __ballot(v != 0);
            const unsigned long long below = mask & ((1ull << lane) - 1ull);
            const int rank = base + __popcll(below);
            if (v != 0 && rank < M_) s_pos[rank] = i * 64 + lane;
            base += __popcll(mask);
        }
        if (lane == 0) s_cnt = (base < M_) ? base : M_;
    }

    // ---- Preload W into registers (reused across all 8 iterations) ----
    const float4* w4 = (const float4*)W;
    const float4 w0 = w4[lane];
    const float4 w1 = w4[lane + 64];
    const float4 w2 = w4[lane + 128];
    const float  bb = bias[0];

    __syncthreads();
    const int count = s_cnt;

    // ---- Phase 2: 32 m-slots per block, 4 waves -> 8 iterations ----
    #pragma unroll
    for (int it = 0; it < M_ / 8; ++it) {
        const int m = half * (M_ / 2) + it * 4 + wave;
        float sum = 0.0f;
        if (m < count) {
            const float4* row4 =
                (const float4*)(enc + ((size_t)b * S_ + s_pos[m]) * D_);
            const float4 r0 = row4[lane];
            const float4 r1 = row4[lane + 64];
            const float4 r2 = row4[lane + 128];
            sum = r0.x * w0.x + r0.y * w0.y + r0.z * w0.z + r0.w * w0.w
                + r1.x * w1.x + r1.y * w1.y + r1.z * w1.z + r1.w * w1.w
                + r2.x * w2.x + r2.y * w2.y + r2.z * w2.z + r2.w * w2.w;
        }
        // 64-lane reduction
        #pragma unroll
        for (int off = 32; off > 0; off >>= 1) {
            sum += __shfl_down(sum, off, 64);
        }
        if (lane == 0) {
            out[(size_t)b * M_ + m] = 1.0f / (1.0f + __expf(-(sum + bb)));
        }
    }
}

extern "C" void kernel_launch(void* const* d_in, const int* in_sizes, int n_in,
                              void* d_out, int out_size, void* d_ws, size_t ws_size,
                              hipStream_t stream) {
    const float* enc  = (const float*)d_in[0];   // (B,S,D) fp32
    const float* W    = (const float*)d_in[1];   // (D,1)  fp32
    const float* bias = (const float*)d_in[2];   // (1,)   fp32
    const int*   cls  = (const int*)d_in[3];     // (B,S)  bool -> int32

    float* out = (float*)d_out;                  // (B,M,1) fp32

    Summarizer_fused_kernel<<<B_ * 2, 256, 0, stream>>>(enc, W, bias, cls, out);
}